// Round 18
// baseline (730.742 us; speedup 1.0000x reference)
//
#include <hip/hip_runtime.h>
#include <cstdint>
#include <cstddef>

#define B_ 2
#define S_ 2048
#define HID_ 2048
#define HK_ 16
#define HV_ 32
#define DK_ 128
#define DV_ 128
#define KEY_DIM_ 2048
#define VAL_DIM_ 4096
#define QKVZ_DIM_ 12288
#define BA_DIM_ 64
#define CONV_DIM_ 8192
#define EPS_ 1e-6f
#define NCHUNK_ 32
#define CL_ 64   // chunk length

typedef unsigned short bf16;
typedef __attribute__((ext_vector_type(8))) short bf16x8;
typedef __attribute__((ext_vector_type(8))) unsigned short u16x8;
typedef __attribute__((ext_vector_type(4))) float f32x4;

__device__ __forceinline__ float silu_f(float x) { return x / (1.f + expf(-x)); }

__device__ __forceinline__ bf16 f2bf(float x) {
    unsigned int u = __float_as_uint(x);
    u += 0x7FFF + ((u >> 16) & 1);   // round-to-nearest-even
    return (bf16)(u >> 16);
}
__device__ __forceinline__ float bf2f(bf16 x) {
    return __uint_as_float((unsigned)x << 16);
}
#define BF2F_LO(u) __uint_as_float((unsigned)(u) << 16)
#define BF2F_HI(u) __uint_as_float((unsigned)(u) & 0xFFFF0000u)

__device__ __forceinline__ float bf_lane(const uint4& x, int j) {
    const unsigned wv = (&x.x)[j >> 1];
    return (j & 1) ? BF2F_HI(wv) : BF2F_LO(wv);
}

typedef const __attribute__((address_space(1))) unsigned int cgu32;
typedef __attribute__((address_space(3))) unsigned int lsu32;
__device__ __forceinline__ void gld16(const void* g, void* l) {
    __builtin_amdgcn_global_load_lds((cgu32*)g, (lsu32*)l, 16, 0, 0);
}

#define MFMA16(a, b, c) __builtin_amdgcn_mfma_f32_16x16x32_bf16((a), (b), (c), 0, 0, 0)

// DPP rotate-add within 16-lane rows (for conv-fused l2norm)
template <int CTRL>
__device__ __forceinline__ float dpp_ror_add(float x) {
    const int t =
        __builtin_amdgcn_update_dpp(0, __float_as_int(x), CTRL, 0xF, 0xF, false);
    return x + __int_as_float(t);
}
__device__ __forceinline__ float row16_sum(float x) {
    x = dpp_ror_add<0x128>(x);
    x = dpp_ror_add<0x124>(x);
    x = dpp_ror_add<0x122>(x);
    x = dpp_ror_add<0x121>(x);
    return x;
}

// ---------------------------------------------------------------------------
// fp32 -> bf16 conversion, fused over hidden | W_qkvz | W_out segments.
// ---------------------------------------------------------------------------
__global__ __launch_bounds__(256) void f2bf3_kernel(
    const float* __restrict__ s0, const float* __restrict__ s1,
    const float* __restrict__ s2, bf16* __restrict__ d0,
    bf16* __restrict__ d1, bf16* __restrict__ d2) {
    const int64_t i = (int64_t)blockIdx.x * 256 + threadIdx.x;  // vec4 index
    const float* src;
    bf16* dst;
    int64_t j;
    if (i < 2097152) {                       // hidden: 8,388,608 elems
        src = s0; dst = d0; j = i;
    } else if (i < 2097152 + 6291456) {      // W_qkvz: 25,165,824 elems
        src = s1; dst = d1; j = i - 2097152;
    } else {                                 // W_out: 8,388,608 elems
        src = s2; dst = d2; j = i - (2097152 + 6291456);
    }
    const float4 v = ((const float4*)src)[j];
    ushort4 o;
    o.x = f2bf(v.x); o.y = f2bf(v.y); o.z = f2bf(v.z); o.w = f2bf(v.w);
    ((ushort4*)dst)[j] = o;
}

// ---------------------------------------------------------------------------
// BMTxBNT-tile bf16 MFMA GEMM NT, 512 threads (8 waves, 2Mx4N), BK=32,
// 3-slot LDS ring, counted vmcnt, setprio, R16 bank swizzle (conflicts=0).
// BMT in {128,256}, BNT in {128,256}. Loads/tile L = BMT/128 + BNT/128;
// prefetch depth 2 tiles -> steady-state wait vmcnt(L).
// ---------------------------------------------------------------------------
template <int BMT, int BNT, int OUTBF16>
__global__ __launch_bounds__(512, 2) void gemm256_nt(
    const bf16* __restrict__ A, const bf16* __restrict__ Bm,
    void* __restrict__ Cv, int M, int N, int K) {
    __shared__ bf16 ringA[3][BMT * 32];
    __shared__ bf16 ringB[3][BNT * 32];
    const int tid = threadIdx.x;
    const int w = tid >> 6;
    const int l = tid & 63;
    const int wm = w >> 2;
    const int wn = w & 3;
    const int fl = l & 15;
    const int fk = (l >> 4) * 8;
    const int bm = blockIdx.y, bn = blockIdx.x;

    const int srow = tid >> 2;
    const int scol = (((tid & 3) ^ ((tid >> 3) & 3)) << 3);
    const bf16* Ag0 = A + (size_t)(bm * BMT + srow) * K + scol;
    const bf16* Ag1 = A + (size_t)(bm * BMT + 128 + srow) * K + scol;  // BMT=256
    const bf16* Bg0 = Bm + (size_t)(bn * BNT + srow) * K + scol;
    const bf16* Bg1 = Bm + (size_t)(bn * BNT + 128 + srow) * K + scol;  // BNT=256

    const int kswz = fk ^ (((fl >> 1) & 3) << 3);
    const int MI = BMT / 32;             // A fragments per wave (8 or 4)
    const int NFR = BNT / 64;            // B fragments per wave (4 or 2)
    int aoff[8], boff[4];
#pragma unroll
    for (int mi = 0; mi < MI; ++mi)
        aoff[mi] = (wm * (BMT / 2) + mi * 16 + fl) * 32 + kswz;
#pragma unroll
    for (int ni = 0; ni < NFR; ++ni)
        boff[ni] = (wn * (BNT / 4) + ni * 16 + fl) * 32 + kswz;

    f32x4 acc[8][4];
#pragma unroll
    for (int mi = 0; mi < MI; ++mi)
#pragma unroll
        for (int ni = 0; ni < NFR; ++ni) acc[mi][ni] = (f32x4){0.f, 0.f, 0.f, 0.f};

#define STAGEX(kt, slot)                                                       \
    do {                                                                       \
        const int _k = (kt) * 32;                                              \
        gld16(Ag0 + _k, &ringA[slot][w * 512]);                                \
        if (BMT == 256) gld16(Ag1 + _k, &ringA[slot][4096 + w * 512]);         \
        gld16(Bg0 + _k, &ringB[slot][w * 512]);                                \
        if (BNT == 256) gld16(Bg1 + _k, &ringB[slot][4096 + w * 512]);         \
    } while (0)

    const int nkt = K >> 5;
    STAGEX(0, 0);
    STAGEX(1, 1);

    for (int t = 0; t < nkt; ++t) {
        const int L = BMT / 128 + BNT / 128;
        if (L == 4)
            asm volatile("s_waitcnt vmcnt(4)" ::: "memory");
        else if (L == 3)
            asm volatile("s_waitcnt vmcnt(3)" ::: "memory");
        else
            asm volatile("s_waitcnt vmcnt(2)" ::: "memory");
        __builtin_amdgcn_s_barrier();
        __builtin_amdgcn_sched_barrier(0);
        const int slot = t % 3;
        const bf16* As_ = ringA[slot];
        const bf16* Bs_ = ringB[slot];
        bf16x8 af[8], bfr[4];
#pragma unroll
        for (int mi = 0; mi < MI; ++mi)
            af[mi] = *(const bf16x8*)(As_ + aoff[mi]);
#pragma unroll
        for (int ni = 0; ni < NFR; ++ni)
            bfr[ni] = *(const bf16x8*)(Bs_ + boff[ni]);
        const int kt2 = (t + 2 < nkt) ? (t + 2) : (nkt - 1);
        STAGEX(kt2, (t + 2) % 3);
        __builtin_amdgcn_s_setprio(1);
#pragma unroll
        for (int mi = 0; mi < MI; ++mi)
#pragma unroll
            for (int ni = 0; ni < NFR; ++ni)
                acc[mi][ni] = MFMA16(af[mi], bfr[ni], acc[mi][ni]);
        __builtin_amdgcn_s_setprio(0);
    }
#undef STAGEX

#pragma unroll
    for (int mi = 0; mi < MI; ++mi)
#pragma unroll
        for (int ni = 0; ni < NFR; ++ni)
#pragma unroll
            for (int r = 0; r < 4; ++r) {
                const int row = bm * BMT + wm * (BMT / 2) + mi * 16 + (l >> 4) * 4 + r;
                const int col = bn * BNT + wn * (BNT / 4) + ni * 16 + fl;
                if (OUTBF16)
                    ((bf16*)Cv)[(size_t)row * N + col] = f2bf(acc[mi][ni][r]);
                else
                    ((float*)Cv)[(size_t)row * N + col] = acc[mi][ni][r];
            }
}

// ---------------------------------------------------------------------------
// ba projection, fp32, K-split x4
// ---------------------------------------------------------------------------
#define BM 64
#define BN 64
#define BKK 32

__global__ __launch_bounds__(256) void gemm_ba_ksplit(
    const float* __restrict__ A, const float* __restrict__ Bm,
    float* __restrict__ Cpart) {
    __shared__ float As[BKK][BM + 4];
    __shared__ float Bs[BKK][BN + 4];
    const int tid = threadIdx.x;
    const int tx = tid & 15;
    const int ty = tid >> 4;
    const int ks = blockIdx.x;     // 0..3
    const int bm = blockIdx.y;     // 0..63
    const float* Ab = A + (size_t)bm * BM * HID_;
    const float* Bb = Bm;
    const int lr = tid >> 2;
    const int lc = (tid & 3) << 3;

    float c[4][4] = {{0.f, 0.f, 0.f, 0.f}, {0.f, 0.f, 0.f, 0.f},
                     {0.f, 0.f, 0.f, 0.f}, {0.f, 0.f, 0.f, 0.f}};

    const int kbeg = ks * 512;
    for (int k0 = kbeg; k0 < kbeg + 512; k0 += BKK) {
        const float4 a0 = *(const float4*)(Ab + (size_t)lr * HID_ + k0 + lc);
        const float4 a1 = *(const float4*)(Ab + (size_t)lr * HID_ + k0 + lc + 4);
        const float4 b0 = *(const float4*)(Bb + (size_t)lr * HID_ + k0 + lc);
        const float4 b1 = *(const float4*)(Bb + (size_t)lr * HID_ + k0 + lc + 4);
        __syncthreads();
        As[lc + 0][lr] = a0.x; As[lc + 1][lr] = a0.y;
        As[lc + 2][lr] = a0.z; As[lc + 3][lr] = a0.w;
        As[lc + 4][lr] = a1.x; As[lc + 5][lr] = a1.y;
        As[lc + 6][lr] = a1.z; As[lc + 7][lr] = a1.w;
        Bs[lc + 0][lr] = b0.x; Bs[lc + 1][lr] = b0.y;
        Bs[lc + 2][lr] = b0.z; Bs[lc + 3][lr] = b0.w;
        Bs[lc + 4][lr] = b1.x; Bs[lc + 5][lr] = b1.y;
        Bs[lc + 6][lr] = b1.z; Bs[lc + 7][lr] = b1.w;
        __syncthreads();
#pragma unroll
        for (int kk = 0; kk < BKK; ++kk) {
            const float4 Av = *(const float4*)&As[kk][ty << 2];
            const float4 Bv = *(const float4*)&Bs[kk][tx << 2];
            const float aa[4] = {Av.x, Av.y, Av.z, Av.w};
            const float bb[4] = {Bv.x, Bv.y, Bv.z, Bv.w};
#pragma unroll
            for (int i = 0; i < 4; ++i)
#pragma unroll
                for (int j = 0; j < 4; ++j)
                    c[i][j] = fmaf(aa[i], bb[j], c[i][j]);
        }
    }
    float* Cp = Cpart + (size_t)ks * ((size_t)B_ * S_ * 64) +
                (size_t)(bm * BM + (ty << 2)) * 64 + (tx << 2);
#pragma unroll
    for (int i = 0; i < 4; ++i)
        *(float4*)(Cp + (size_t)i * 64) =
            make_float4(c[i][0], c[i][1], c[i][2], c[i][3]);
}

// ---------------------------------------------------------------------------
// Causal depthwise conv (K=4) + SiLU + FUSED q/k l2norm, 8 ch/thread.
// ---------------------------------------------------------------------------
__global__ __launch_bounds__(256) void conv_silu_kernel(
    const bf16* __restrict__ qkvz, const float* __restrict__ cw,
    bf16* __restrict__ qbf, bf16* __restrict__ kbf, bf16* __restrict__ vbuf,
    bf16* __restrict__ zbuf) {
    const int64_t idx = (int64_t)blockIdx.x * 256 + threadIdx.x;
    const int cg = (int)(idx % 1536);
    const int64_t bs = idx / 1536;
    const int s = (int)(bs & (S_ - 1));
    const int c0 = cg << 3;

    int col;
    bf16* outp;
    if (c0 < KEY_DIM_) {
        col = ((c0 >> 7) * 768) + (c0 & 127);
        outp = qbf + bs * KEY_DIM_ + c0;
    } else if (c0 < 2 * KEY_DIM_) {
        const int c2 = c0 - KEY_DIM_;
        col = ((c2 >> 7) * 768) + 128 + (c2 & 127);
        outp = kbf + bs * KEY_DIM_ + c2;
    } else if (c0 < 2 * KEY_DIM_ + VAL_DIM_) {
        const int c3 = c0 - 2 * KEY_DIM_;
        col = ((c3 >> 8) * 768) + 256 + (c3 & 255);
        outp = vbuf + bs * VAL_DIM_ + c3;
    } else {
        const int zc = c0 - (2 * KEY_DIM_ + VAL_DIM_);
        const int hv = zc >> 7;
        col = (hv >> 1) * 768 + 512 + (hv & 1) * 128 + (zc & 127);
        outp = zbuf + bs * VAL_DIM_ + zc;
    }
    const bf16* xp = qkvz + bs * (int64_t)QKVZ_DIM_ + col;
    if (c0 >= 2 * KEY_DIM_ + VAL_DIM_) {
        *(uint4*)outp = *(const uint4*)xp;   // z passthrough
        return;
    }
    const uint4 zero4 = {0u, 0u, 0u, 0u};
    const uint4 x0 = *(const uint4*)xp;
    const uint4 x1 = (s >= 1) ? *(const uint4*)(xp - QKVZ_DIM_) : zero4;
    const uint4 x2 = (s >= 2) ? *(const uint4*)(xp - 2 * QKVZ_DIM_) : zero4;
    const uint4 x3 = (s >= 3) ? *(const uint4*)(xp - 3 * QKVZ_DIM_) : zero4;
    float y[8];
#pragma unroll
    for (int j = 0; j < 8; ++j) {
        const float4 wv = *(const float4*)(cw + (size_t)(c0 + j) * 4);
        float acc = wv.w * bf_lane(x0, j);
        acc = fmaf(wv.z, bf_lane(x1, j), acc);
        acc = fmaf(wv.y, bf_lane(x2, j), acc);
        acc = fmaf(wv.x, bf_lane(x3, j), acc);
        y[j] = silu_f(acc);
    }
    float sc = 1.f;
    if (c0 < 2 * KEY_DIM_) {   // q or k: l2norm across the 128-ch head row
        float ss = 0.f;
#pragma unroll
        for (int j = 0; j < 8; ++j) ss = fmaf(y[j], y[j], ss);
        ss = row16_sum(ss);    // 16 lanes x 8 ch = one head row
        sc = rsqrtf(ss + EPS_);
        if (c0 < KEY_DIM_) sc *= 0.08838834764831845f;  // DK^-0.5 for q
    }
    u16x8 o;
#pragma unroll
    for (int j = 0; j < 8; ++j) o[j] = f2bf(y[j] * sc);
    *(u16x8*)outp = o;
}

// ---------------------------------------------------------------------------
// Gate precompute from 4 K-split partials
// ---------------------------------------------------------------------------
__global__ __launch_bounds__(256) void gate_kernel(
    const float* __restrict__ ba_part, const float* __restrict__ A_log,
    const float* __restrict__ dt_bias, float* __restrict__ gbuf,
    float* __restrict__ betabuf) {
    const int idx = blockIdx.x * 256 + threadIdx.x;   // B*S*HV
    const int hv = idx & (HV_ - 1);
    const int bs = idx >> 5;
    const int hk = hv >> 1, j = hv & 1;
    const size_t SP = (size_t)B_ * S_ * 64;  // 262144
    const float* p = ba_part + (size_t)bs * 64 + hk * 4;
    const float bval = p[j] + p[SP + j] + p[2 * SP + j] + p[3 * SP + j];
    const float aval =
        p[2 + j] + p[SP + 2 + j] + p[2 * SP + 2 + j] + p[3 * SP + 2 + j];
    const float x = aval + dt_bias[hv];
    const float sp = (x > 20.f) ? x : log1pf(expf(x));
    gbuf[idx] = -expf(A_log[hv]) * sp;
    betabuf[idx] = 1.f / (1.f + expf(-bval));
}

// ---------------------------------------------------------------------------
// PASS 1 — R15 structure (register substitution + wave specialization).
// ---------------------------------------------------------------------------
__global__ __launch_bounds__(256) void p1_kernel(
    const bf16* __restrict__ qbf, const bf16* __restrict__ kbf,
    const bf16* __restrict__ vbuf, const float* __restrict__ gbuf,
    const float* __restrict__ betabuf, bf16* __restrict__ WkA,
    bf16* __restrict__ QgA, bf16* __restrict__ Kg2A, bf16* __restrict__ UA,
    bf16* __restrict__ LA, float* __restrict__ gcArr) {
    const int ch = blockIdx.x;          // bh*32 + c
    const int bh = ch >> 5, c = ch & 31;
    const int b = bh >> 5, hv = bh & 31;
    const int hk = hv >> 1;
    const int tid = threadIdx.x;
    const int w = tid >> 6, l = tid & 63;
    const int fl = l & 15, fk = (l >> 4) * 8;

    __shared__ float Gls[CL_];
    __shared__ float Bls[CL_];
    __shared__ float Egt[CL_];          // exp(G_t)
    __shared__ float Egc[CL_];          // exp(G63 - G_t)
    __shared__ float A_ls[CL_][CL_ + 1];
    __shared__ bf16 Tbf[CL_ * CL_];
    __shared__ bf16 Vt[128 * 72];
    __shared__ bf16 Kt[128 * 72];

    if (tid < 64) {
        float G = gbuf[((size_t)(b * S_ + c * 64 + tid)) * HV_ + hv];
        Bls[tid] = betabuf[((size_t)(b * S_ + c * 64 + tid)) * HV_ + hv];
#pragma unroll
        for (int d = 1; d < 64; d <<= 1) {
            const float n = __shfl_up(G, d, 64);
            if (tid >= d) G += n;
        }
        Gls[tid] = G;
        const float eg = expf(G);
        Egt[tid] = eg;
        Egc[tid] = expf(__shfl(G, 63, 64) - G);
        if (tid == 63) gcArr[ch] = eg;
    }
    __syncthreads();

    const bf16* kc = kbf + ((size_t)(b * S_ + c * 64)) * KEY_DIM_ + hk * DK_;
    const bf16* qc = qbf + ((size_t)(b * S_ + c * 64)) * KEY_DIM_ + hk * DK_;
    bf16* LC = LA + (size_t)ch * 4096;

    f32x4 accK[4], accQ[4];
#pragma unroll
    for (int n = 0; n < 4; ++n) {
        accK[n] = (f32x4){0.f, 0.f, 0.f, 0.f};
        accQ[n] = (f32x4){0.f, 0.f, 0.f, 0.f};
    }
#pragma unroll
    for (int kk = 0; kk < 4; ++kk) {
        const bf16x8 aK =
            *(const bf16x8*)(kc + (size_t)(w * 16 + fl) * KEY_DIM_ + fk + 32 * kk);
        const bf16x8 aQ =
            *(const bf16x8*)(qc + (size_t)(w * 16 + fl) * KEY_DIM_ + fk + 32 * kk);
#pragma unroll
        for (int n = 0; n < 4; ++n) {
            const bf16x8 bK = *(const bf16x8*)(kc + (size_t)(n * 16 + fl) * KEY_DIM_ +
                                               fk + 32 * kk);
            accK[n] = MFMA16(aK, bK, accK[n]);
            accQ[n] = MFMA16(aQ, bK, accQ[n]);
        }
    }
#pragma unroll
    for (int n = 0; n < 4; ++n)
#pragma unroll
        for (int r = 0; r < 4; ++r) {
            const int t = w * 16 + (l >> 4) * 4 + r;
            const int s = n * 16 + fl;
            const float eg = expf(Gls[t] - Gls[s]);
            A_ls[t][s] = (s < t) ? Bls[t] * eg * accK[n][r] : 0.f;
            const float lv = (s <= t) ? eg * accQ[n][r] : 0.f;
            LC[t * 64 + s] = f2bf(lv);
        }
    __syncthreads();

    bf16* QgC = QgA + (size_t)ch * 8192;
    bf16* KgC = Kg2A + (size_t)ch * 8192;

    if (w == 0) {
        float Tcol[64];
#pragma unroll
        for (int t = 0; t < 64; ++t) {
            float acc = (t == l) ? 1.f : 0.f;
#pragma unroll
            for (int s = 0; s < t; ++s)
                acc = fmaf(-A_ls[t][s], Tcol[s], acc);
            Tcol[t] = acc;
            Tbf[t * 64 + l] = f2bf(acc);
        }
    } else if (w == 1) {
        for (int i = l; i < 8192; i += 64) {
            const int d = i & 127, s = i >> 7;
            Vt[d * 72 + s] = f2bf(
                bf2f(vbuf[((size_t)(b * S_ + c * 64 + s)) * VAL_DIM_ + hv * DV_ + d]) *
                Bls[s]);
        }
    } else if (w == 2) {
        for (int i = l; i < 8192; i += 64) {
            const int d = i & 127, s = i >> 7;
            Kt[d * 72 + s] =
                f2bf(bf2f(kc[(size_t)s * KEY_DIM_ + d]) * Bls[s] * Egt[s]);
        }
    } else {
        for (int i = l; i < 8192; i += 64) {
            const int d = i & 127, t = i >> 7;
            QgC[t * 128 + d] = f2bf(bf2f(qc[(size_t)t * KEY_DIM_ + d]) * Egt[t]);
            KgC[d * 64 + t] = f2bf(bf2f(kc[(size_t)t * KEY_DIM_ + d]) * Egc[t]);
        }
    }
    __syncthreads();

    bf16* UC = UA + (size_t)ch * 8192;
    bf16* WkC = WkA + (size_t)ch * 8192;
    f32x4 accU[8], accW[8];
#pragma unroll
    for (int n = 0; n < 8; ++n) {
        accU[n] = (f32x4){0.f, 0.f, 0.f, 0.f};
        accW[n] = (f32x4){0.f, 0.f, 0.f, 0.f};
    }
#pragma unroll
    for (int kk = 0; kk < 2; ++kk) {
        const bf16x8 aT = *(const bf16x8*)(Tbf + (w * 16 + fl) * 64 + fk + 32 * kk);
#pragma unroll
        for (int n = 0; n < 8; ++n) {
            const bf16x8 bV = *(const bf16x8*)(Vt + (n * 16 + fl) * 72 + fk + 32 * kk);
            const bf16x8 bK2 = *(const bf16x8*)(Kt + (n * 16 + fl) * 72 + fk + 32 * kk);
            accU[n] = MFMA16(aT, bV, accU[n]);
            accW[n] = MFMA16(aT, bK2, accW[n]);
        }
    }
#pragma unroll
    for (int n = 0; n < 8; ++n)
#pragma unroll
        for (int r = 0; r < 4; ++r) {
            const int t = w * 16 + (l >> 4) * 4 + r;
            const int col = n * 16 + fl;
            UC[t * 128 + col] = f2bf(accU[n][r]);
            WkC[t * 128 + col] = f2bf(accW[n][r]);
        }
}

// ---------------------------------------------------------------------------
// PASS 2 — unchanged from R12.
// ---------------------------------------------------------------------------
__global__ __launch_bounds__(256) void p2_kernel(
    const bf16* __restrict__ WkA, const bf16* __restrict__ QgA,
    const bf16* __restrict__ Kg2A, const bf16* __restrict__ UA,
    const bf16* __restrict__ LA, const float* __restrict__ gcArr,
    bf16* __restrict__ core) {
    const int xcd = blockIdx.x & 7;
    const int rr = blockIdx.x >> 3;       // 0..31
    const int bh = xcd * 8 + (rr & 7);    // 0..63
    const int dvb = rr >> 3;              // 0..3
    const int b = bh >> 5, hv = bh & 31;
    const int tid = threadIdx.x;
    const int w = tid >> 6, l = tid & 63;
    const int fl = l & 15, fk = (l >> 4) * 8;

    __shared__ bf16 Sbf[32 * 136];
    __shared__ bf16 Dbf[32 * 72];

    for (int i = tid; i < 32 * 136; i += 256) Sbf[i] = 0;
    f32x4 accS[2][2];
#pragma unroll
    for (int m = 0; m < 2; ++m)
#pragma unroll
        for (int n = 0; n < 2; ++n) accS[m][n] = (f32x4){0.f, 0.f, 0.f, 0.f};
    __syncthreads();

    for (int c = 0; c < NCHUNK_; ++c) {
        const size_t ch = (size_t)bh * 32 + c;
        const bf16* WkC = WkA + ch * 8192;
        const bf16* QgC = QgA + ch * 8192;
        const bf16* KgC = Kg2A + ch * 8192;
        const bf16* UC = UA + ch * 8192;
        const bf16* LC = LA + ch * 4096;

        f32x4 accD[2], accO[2];
#pragma unroll
        for (int n = 0; n < 2; ++n) {
            accD[n] = (f32x4){0.f, 0.f, 0.f, 0.f};
            accO[n] = (f32x4){0.f, 0.f, 0.f, 0.f};
        }
#pragma unroll
        for (int kk = 0; kk < 4; ++kk) {
            const bf16x8 bS0 = *(const bf16x8*)(Sbf + (0 * 16 + fl) * 136 + fk + 32 * kk);
            const bf16x8 bS1 = *(const bf16x8*)(Sbf + (1 * 16 + fl) * 136 + fk + 32 * kk);
            const bf16x8 aW = *(const bf16x8*)(WkC + (w * 16 + fl) * 128 + fk + 32 * kk);
            const bf16x8 aQ = *(const bf16x8*)(QgC + (w * 16 + fl) * 128 + fk + 32 * kk);
            accD[0] = MFMA16(aW, bS0, accD[0]);
            accD[1] = MFMA16(aW, bS1, accD[1]);
            accO[0] = MFMA16(aQ, bS0, accO[0]);
            accO[1] = MFMA16(aQ, bS1, accO[1]);
        }
#pragma unroll
        for (int n = 0; n < 2; ++n)
#pragma unroll
            for (int r = 0; r < 4; ++r) {
                const int t = w * 16 + (l >> 4) * 4 + r;
                const int dvl = n * 16 + fl;
                const float u = bf2f(UC[t * 128 + dvb * 32 + dvl]);
                Dbf[dvl * 72 + t] = f2bf(u - accD[n][r]);
            }
        __syncthreads();

#pragma unroll
        for (int kk = 0; kk < 2; ++kk) {
            const bf16x8 bD0 = *(const bf16x8*)(Dbf + (0 * 16 + fl) * 72 + fk + 32 * kk);
            const bf16x8 bD1 = *(const bf16x8*)(Dbf + (1 * 16 + fl) * 72 + fk + 32 * kk);
            const bf16x8 aL = *(const bf16x8*)(LC + (w * 16 + fl) * 64 + fk + 32 * kk);
            accO[0] = MFMA16(aL, bD0, accO[0]);
            accO[1] = MFMA16(aL, bD1, accO[1]);
        }
#pragma unroll
        for (int n = 0; n < 2; ++n)
#pragma unroll
            for (int r = 0; r < 4; ++r) {
                const int t = w * 16 + (l >> 4) * 4 + r;
                const int col = hv * 128 + dvb * 32 + n * 16 + fl;
                core[((size_t)(b * S_ + c * 64 + t)) * VAL_DIM_ + col] =
                    f2bf(accO[n][r]);
            }

        const float gc = gcArr[ch];
#pragma unroll
        for (int m = 0; m < 2; ++m)
#pragma unroll
            for (int n = 0; n < 2; ++n)
#pragma unroll
                for (int r = 0; r < 4; ++r) accS[m][n][r] *= gc;
#pragma unroll
        for (int kk = 0; kk < 2; ++kk) {
            const bf16x8 bD0 = *(const bf16x8*)(Dbf + (0 * 16 + fl) * 72 + fk + 32 * kk);
            const bf16x8 bD1 = *(const bf16x8*)(Dbf + (1 * 16 + fl) * 72 + fk + 32 * kk);
#pragma unroll
            for (int m = 0; m < 2; ++m) {
                const bf16x8 aK =
                    *(const bf16x8*)(KgC + ((2 * w + m) * 16 + fl) * 64 + fk + 32 * kk);
                accS[m][0] = MFMA16(aK, bD0, accS[m][0]);
                accS[m][1] = MFMA16(aK, bD1, accS[m][1]);
            }
        }
        __syncthreads();
#pragma unroll
        for (int m = 0; m < 2; ++m)
#pragma unroll
            for (int n = 0; n < 2; ++n)
#pragma unroll
                for (int r = 0; r < 4; ++r) {
                    const int dk = (2 * w + m) * 16 + (l >> 4) * 4 + r;
                    const int dvl = n * 16 + fl;
                    Sbf[dvl * 136 + dk] = f2bf(accS[m][n][r]);
                }
        __syncthreads();
    }
}

// ---------------------------------------------------------------------------
// Gated RMSNorm in-place on bf16 core; z from zbuf (contiguous).
// ---------------------------------------------------------------------------
__global__ __launch_bounds__(256) void rmsnorm_gate_kernel(
    bf16* __restrict__ core, const bf16* __restrict__ zbuf,
    const float* __restrict__ nw) {
    const int wid = (blockIdx.x * 256 + threadIdx.x) >> 6;
    const int lane = threadIdx.x & 63;
    const int hv = wid & (HV_ - 1);
    const int64_t bs = wid >> 5;
    bf16* x = core + (size_t)bs * VAL_DIM_ + hv * DV_;
    const float x0 = bf2f(x[lane]);
    const float x1 = bf2f(x[lane + 64]);
    float ss = fmaf(x0, x0, x1 * x1);
#pragma unroll
    for (int m = 1; m < 64; m <<= 1) ss += __shfl_xor(ss, m);
    const float inv = rsqrtf(ss * (1.f / 128.f) + EPS_);
    const bf16* z = zbuf + (size_t)bs * VAL_DIM_ + hv * DV_;
    x[lane] = f2bf(x0 * inv * nw[lane] * silu_f(bf2f(z[lane])));
    x[lane + 64] =
        f2bf(x1 * inv * nw[lane + 64] * silu_f(bf2f(z[lane + 64])));
}

// ---------------------------------------------------------------------------
extern "C" void kernel_launch(void* const* d_in, const int* in_sizes, int n_in,
                              void* d_out, int out_size, void* d_ws,
                              size_t ws_size, hipStream_t stream) {
    const float* hidden  = (const float*)d_in[0];
    const float* W_qkvz  = (const float*)d_in[1];
    const float* W_ba    = (const float*)d_in[2];
    const float* conv_w  = (const float*)d_in[3];
    const float* dt_bias = (const float*)d_in[4];
    const float* A_log   = (const float*)d_in[5];
    const float* norm_w  = (const float*)d_in[6];
    const float* W_out   = (const float*)d_in[7];
    float* out = (float*)d_out;

    // ---- workspace (~324 MB <= proven 337.5) ----
    bf16* R = (bf16*)d_ws;
    bf16* hidden_bf = R;                         //  8,388,608 e
    bf16* Wq_bf = R + (size_t)8388608;           // 25,165,824 e
    bf16* qkvz  = R + (size_t)33554432;          // 50,331,648 e
    // P1 aliases (valid once conv has consumed qkvz):
    bf16* WkA  = R;                              // 16,777,216 e
    bf16* QgA  = R + (size_t)16777216;           // 16,777,216 e
    bf16* Kg2A = R + (size_t)33554432;           // 16,777,216 e
    bf16* UA   = R + (size_t)50331648;           // 16,777,216 e
    bf16* LA   = R + (size_t)67108864;           //  8,388,608 e
    // non-aliased:
    bf16* Wo_bf = R + (size_t)83886080;          //  8,388,608 e
    bf16* qbf   = Wo_bf + (size_t)8388608;       //  8,388,608 e
    bf16* kbf   = qbf + (size_t)8388608;         //  8,388,608 e
    bf16* vbuf  = kbf + (size_t)8388608;         // 16,777,216 e
    bf16* zbuf  = vbuf + (size_t)16777216;       // 16,777,216 e
    bf16* core  = zbuf + (size_t)16777216;       // 16,777,216 e
    float* ba_part = (float*)(core + (size_t)16777216);  // 1,048,576 f
    float* gbuf    = ba_part + 1048576;                  //   131,072 f
    float* betabuf = gbuf + 131072;                      //   131,072 f
    float* gcArr   = betabuf + 131072;                   //     2,048 f

    const int MBS = B_ * S_;  // 4096

    // 0. fp32 -> bf16 operand conversion (one fused launch)
    f2bf3_kernel<<<40960, 256, 0, stream>>>(hidden, W_qkvz, W_out, hidden_bf,
                                            Wq_bf, Wo_bf);

    // 1. qkvz = hidden @ W_qkvz^T (128x256 tiles, 1536 WGs = 3 uniform rounds)
    gemm256_nt<128, 256, 1><<<dim3(QKVZ_DIM_ / 256, MBS / 128), 512, 0,
                              stream>>>(hidden_bf, Wq_bf, (void*)qkvz, MBS,
                                        QKVZ_DIM_, HID_);
    // 2. ba = hidden @ W_ba^T (fp32, K-split x4)
    gemm_ba_ksplit<<<dim3(4, 64), 256, 0, stream>>>(hidden, W_ba, ba_part);
    // 3. gates
    gate_kernel<<<(MBS * HV_) / 256, 256, 0, stream>>>(ba_part, A_log, dt_bias,
                                                       gbuf, betabuf);
    // 4. conv + silu + fused q/k l2norm + z copy
    conv_silu_kernel<<<(int)(((int64_t)MBS * 1536) / 256), 256, 0, stream>>>(
        qkvz, conv_w, qbf, kbf, vbuf, zbuf);
    // 5. chunked delta rule
    p1_kernel<<<2048, 256, 0, stream>>>(qbf, kbf, vbuf, gbuf, betabuf, WkA,
                                        QgA, Kg2A, UA, LA, gcArr);
    p2_kernel<<<256, 256, 0, stream>>>(WkA, QgA, Kg2A, UA, LA, gcArr, core);
    // 6. gated rmsnorm
    rmsnorm_gate_kernel<<<(MBS * HV_ * 64) / 256, 256, 0, stream>>>(core, zbuf,
                                                                    norm_w);
    // 7. out = core @ W_out^T (128x128 tiles, 512 WGs = 1 round, fp32 out)
    gemm256_nt<128, 128, 0><<<dim3(HID_ / 128, MBS / 128), 512, 0, stream>>>(
        core, Wo_bf, (void*)out, MBS, HID_, VAL_DIM_);
}

// Round 19
// 704.722 us; speedup vs baseline: 1.0369x; 1.0369x over previous
//
#include <hip/hip_runtime.h>
#include <cstdint>
#include <cstddef>

#define B_ 2
#define S_ 2048
#define HID_ 2048
#define HK_ 16
#define HV_ 32
#define DK_ 128
#define DV_ 128
#define KEY_DIM_ 2048
#define VAL_DIM_ 4096
#define QKVZ_DIM_ 12288
#define BA_DIM_ 64
#define CONV_DIM_ 8192
#define EPS_ 1e-6f
#define NCHUNK_ 32
#define CL_ 64   // chunk length

typedef unsigned short bf16;
typedef __attribute__((ext_vector_type(8))) short bf16x8;
typedef __attribute__((ext_vector_type(8))) unsigned short u16x8;
typedef __attribute__((ext_vector_type(4))) float f32x4;

__device__ __forceinline__ float silu_f(float x) { return x / (1.f + expf(-x)); }

__device__ __forceinline__ bf16 f2bf(float x) {
    unsigned int u = __float_as_uint(x);
    u += 0x7FFF + ((u >> 16) & 1);   // round-to-nearest-even
    return (bf16)(u >> 16);
}
__device__ __forceinline__ float bf2f(bf16 x) {
    return __uint_as_float((unsigned)x << 16);
}
#define BF2F_LO(u) __uint_as_float((unsigned)(u) << 16)
#define BF2F_HI(u) __uint_as_float((unsigned)(u) & 0xFFFF0000u)

__device__ __forceinline__ float bf_lane(const uint4& x, int j) {
    const unsigned wv = (&x.x)[j >> 1];
    return (j & 1) ? BF2F_HI(wv) : BF2F_LO(wv);
}

typedef const __attribute__((address_space(1))) unsigned int cgu32;
typedef __attribute__((address_space(3))) unsigned int lsu32;
__device__ __forceinline__ void gld16(const void* g, void* l) {
    __builtin_amdgcn_global_load_lds((cgu32*)g, (lsu32*)l, 16, 0, 0);
}

#define MFMA16(a, b, c) __builtin_amdgcn_mfma_f32_16x16x32_bf16((a), (b), (c), 0, 0, 0)

// DPP rotate-add within 16-lane rows (for conv-fused l2norm)
template <int CTRL>
__device__ __forceinline__ float dpp_ror_add(float x) {
    const int t =
        __builtin_amdgcn_update_dpp(0, __float_as_int(x), CTRL, 0xF, 0xF, false);
    return x + __int_as_float(t);
}
__device__ __forceinline__ float row16_sum(float x) {
    x = dpp_ror_add<0x128>(x);
    x = dpp_ror_add<0x124>(x);
    x = dpp_ror_add<0x122>(x);
    x = dpp_ror_add<0x121>(x);
    return x;
}

// ---------------------------------------------------------------------------
// fp32 -> bf16 conversion, fused over hidden | W_qkvz | W_out segments.
// ---------------------------------------------------------------------------
__global__ __launch_bounds__(256) void f2bf3_kernel(
    const float* __restrict__ s0, const float* __restrict__ s1,
    const float* __restrict__ s2, bf16* __restrict__ d0,
    bf16* __restrict__ d1, bf16* __restrict__ d2) {
    const int64_t i = (int64_t)blockIdx.x * 256 + threadIdx.x;  // vec4 index
    const float* src;
    bf16* dst;
    int64_t j;
    if (i < 2097152) {                       // hidden: 8,388,608 elems
        src = s0; dst = d0; j = i;
    } else if (i < 2097152 + 6291456) {      // W_qkvz: 25,165,824 elems
        src = s1; dst = d1; j = i - 2097152;
    } else {                                 // W_out: 8,388,608 elems
        src = s2; dst = d2; j = i - (2097152 + 6291456);
    }
    const float4 v = ((const float4*)src)[j];
    ushort4 o;
    o.x = f2bf(v.x); o.y = f2bf(v.y); o.z = f2bf(v.z); o.w = f2bf(v.w);
    ((ushort4*)dst)[j] = o;
}

// ---------------------------------------------------------------------------
// BMTxBNT-tile bf16 MFMA GEMM NT, 512 threads (8 waves, 2Mx4N), BK=32,
// 3-slot LDS ring, counted vmcnt, setprio, R16 bank swizzle (conflicts=0).
// 256x256 best measured (R16: 189us, MfmaUtil 50%, 1 WG/CU deep-ring).
// ---------------------------------------------------------------------------
template <int BMT, int BNT, int OUTBF16>
__global__ __launch_bounds__(512, 2) void gemm256_nt(
    const bf16* __restrict__ A, const bf16* __restrict__ Bm,
    void* __restrict__ Cv, int M, int N, int K) {
    __shared__ bf16 ringA[3][BMT * 32];
    __shared__ bf16 ringB[3][BNT * 32];
    const int tid = threadIdx.x;
    const int w = tid >> 6;
    const int l = tid & 63;
    const int wm = w >> 2;
    const int wn = w & 3;
    const int fl = l & 15;
    const int fk = (l >> 4) * 8;
    const int bm = blockIdx.y, bn = blockIdx.x;

    const int srow = tid >> 2;
    const int scol = (((tid & 3) ^ ((tid >> 3) & 3)) << 3);
    const bf16* Ag0 = A + (size_t)(bm * BMT + srow) * K + scol;
    const bf16* Ag1 = A + (size_t)(bm * BMT + 128 + srow) * K + scol;  // BMT=256
    const bf16* Bg0 = Bm + (size_t)(bn * BNT + srow) * K + scol;
    const bf16* Bg1 = Bm + (size_t)(bn * BNT + 128 + srow) * K + scol;  // BNT=256

    const int kswz = fk ^ (((fl >> 1) & 3) << 3);
    const int MI = BMT / 32;             // A fragments per wave (8 or 4)
    const int NFR = BNT / 64;            // B fragments per wave (4 or 2)
    int aoff[8], boff[4];
#pragma unroll
    for (int mi = 0; mi < MI; ++mi)
        aoff[mi] = (wm * (BMT / 2) + mi * 16 + fl) * 32 + kswz;
#pragma unroll
    for (int ni = 0; ni < NFR; ++ni)
        boff[ni] = (wn * (BNT / 4) + ni * 16 + fl) * 32 + kswz;

    f32x4 acc[8][4];
#pragma unroll
    for (int mi = 0; mi < MI; ++mi)
#pragma unroll
        for (int ni = 0; ni < NFR; ++ni) acc[mi][ni] = (f32x4){0.f, 0.f, 0.f, 0.f};

#define STAGEX(kt, slot)                                                       \
    do {                                                                       \
        const int _k = (kt) * 32;                                              \
        gld16(Ag0 + _k, &ringA[slot][w * 512]);                                \
        if (BMT == 256) gld16(Ag1 + _k, &ringA[slot][4096 + w * 512]);         \
        gld16(Bg0 + _k, &ringB[slot][w * 512]);                                \
        if (BNT == 256) gld16(Bg1 + _k, &ringB[slot][4096 + w * 512]);         \
    } while (0)

    const int nkt = K >> 5;
    STAGEX(0, 0);
    STAGEX(1, 1);

    for (int t = 0; t < nkt; ++t) {
        const int L = BMT / 128 + BNT / 128;
        if (L == 4)
            asm volatile("s_waitcnt vmcnt(4)" ::: "memory");
        else if (L == 3)
            asm volatile("s_waitcnt vmcnt(3)" ::: "memory");
        else
            asm volatile("s_waitcnt vmcnt(2)" ::: "memory");
        __builtin_amdgcn_s_barrier();
        __builtin_amdgcn_sched_barrier(0);
        const int slot = t % 3;
        const bf16* As_ = ringA[slot];
        const bf16* Bs_ = ringB[slot];
        bf16x8 af[8], bfr[4];
#pragma unroll
        for (int mi = 0; mi < MI; ++mi)
            af[mi] = *(const bf16x8*)(As_ + aoff[mi]);
#pragma unroll
        for (int ni = 0; ni < NFR; ++ni)
            bfr[ni] = *(const bf16x8*)(Bs_ + boff[ni]);
        const int kt2 = (t + 2 < nkt) ? (t + 2) : (nkt - 1);
        STAGEX(kt2, (t + 2) % 3);
        __builtin_amdgcn_s_setprio(1);
#pragma unroll
        for (int mi = 0; mi < MI; ++mi)
#pragma unroll
            for (int ni = 0; ni < NFR; ++ni)
                acc[mi][ni] = MFMA16(af[mi], bfr[ni], acc[mi][ni]);
        __builtin_amdgcn_s_setprio(0);
    }
#undef STAGEX

#pragma unroll
    for (int mi = 0; mi < MI; ++mi)
#pragma unroll
        for (int ni = 0; ni < NFR; ++ni)
#pragma unroll
            for (int r = 0; r < 4; ++r) {
                const int row = bm * BMT + wm * (BMT / 2) + mi * 16 + (l >> 4) * 4 + r;
                const int col = bn * BNT + wn * (BNT / 4) + ni * 16 + fl;
                if (OUTBF16)
                    ((bf16*)Cv)[(size_t)row * N + col] = f2bf(acc[mi][ni][r]);
                else
                    ((float*)Cv)[(size_t)row * N + col] = acc[mi][ni][r];
            }
}

// ---------------------------------------------------------------------------
// ba projection, fp32, K-split x4
// ---------------------------------------------------------------------------
#define BM 64
#define BN 64
#define BKK 32

__global__ __launch_bounds__(256) void gemm_ba_ksplit(
    const float* __restrict__ A, const float* __restrict__ Bm,
    float* __restrict__ Cpart) {
    __shared__ float As[BKK][BM + 4];
    __shared__ float Bs[BKK][BN + 4];
    const int tid = threadIdx.x;
    const int tx = tid & 15;
    const int ty = tid >> 4;
    const int ks = blockIdx.x;     // 0..3
    const int bm = blockIdx.y;     // 0..63
    const float* Ab = A + (size_t)bm * BM * HID_;
    const float* Bb = Bm;
    const int lr = tid >> 2;
    const int lc = (tid & 3) << 3;

    float c[4][4] = {{0.f, 0.f, 0.f, 0.f}, {0.f, 0.f, 0.f, 0.f},
                     {0.f, 0.f, 0.f, 0.f}, {0.f, 0.f, 0.f, 0.f}};

    const int kbeg = ks * 512;
    for (int k0 = kbeg; k0 < kbeg + 512; k0 += BKK) {
        const float4 a0 = *(const float4*)(Ab + (size_t)lr * HID_ + k0 + lc);
        const float4 a1 = *(const float4*)(Ab + (size_t)lr * HID_ + k0 + lc + 4);
        const float4 b0 = *(const float4*)(Bb + (size_t)lr * HID_ + k0 + lc);
        const float4 b1 = *(const float4*)(Bb + (size_t)lr * HID_ + k0 + lc + 4);
        __syncthreads();
        As[lc + 0][lr] = a0.x; As[lc + 1][lr] = a0.y;
        As[lc + 2][lr] = a0.z; As[lc + 3][lr] = a0.w;
        As[lc + 4][lr] = a1.x; As[lc + 5][lr] = a1.y;
        As[lc + 6][lr] = a1.z; As[lc + 7][lr] = a1.w;
        Bs[lc + 0][lr] = b0.x; Bs[lc + 1][lr] = b0.y;
        Bs[lc + 2][lr] = b0.z; Bs[lc + 3][lr] = b0.w;
        Bs[lc + 4][lr] = b1.x; Bs[lc + 5][lr] = b1.y;
        Bs[lc + 6][lr] = b1.z; Bs[lc + 7][lr] = b1.w;
        __syncthreads();
#pragma unroll
        for (int kk = 0; kk < BKK; ++kk) {
            const float4 Av = *(const float4*)&As[kk][ty << 2];
            const float4 Bv = *(const float4*)&Bs[kk][tx << 2];
            const float aa[4] = {Av.x, Av.y, Av.z, Av.w};
            const float bb[4] = {Bv.x, Bv.y, Bv.z, Bv.w};
#pragma unroll
            for (int i = 0; i < 4; ++i)
#pragma unroll
                for (int j = 0; j < 4; ++j)
                    c[i][j] = fmaf(aa[i], bb[j], c[i][j]);
        }
    }
    float* Cp = Cpart + (size_t)ks * ((size_t)B_ * S_ * 64) +
                (size_t)(bm * BM + (ty << 2)) * 64 + (tx << 2);
#pragma unroll
    for (int i = 0; i < 4; ++i)
        *(float4*)(Cp + (size_t)i * 64) =
            make_float4(c[i][0], c[i][1], c[i][2], c[i][3]);
}

// ---------------------------------------------------------------------------
// Causal depthwise conv (K=4) + SiLU + FUSED q/k l2norm, 8 ch/thread.
// ---------------------------------------------------------------------------
__global__ __launch_bounds__(256) void conv_silu_kernel(
    const bf16* __restrict__ qkvz, const float* __restrict__ cw,
    bf16* __restrict__ qbf, bf16* __restrict__ kbf, bf16* __restrict__ vbuf,
    bf16* __restrict__ zbuf) {
    const int64_t idx = (int64_t)blockIdx.x * 256 + threadIdx.x;
    const int cg = (int)(idx % 1536);
    const int64_t bs = idx / 1536;
    const int s = (int)(bs & (S_ - 1));
    const int c0 = cg << 3;

    int col;
    bf16* outp;
    if (c0 < KEY_DIM_) {
        col = ((c0 >> 7) * 768) + (c0 & 127);
        outp = qbf + bs * KEY_DIM_ + c0;
    } else if (c0 < 2 * KEY_DIM_) {
        const int c2 = c0 - KEY_DIM_;
        col = ((c2 >> 7) * 768) + 128 + (c2 & 127);
        outp = kbf + bs * KEY_DIM_ + c2;
    } else if (c0 < 2 * KEY_DIM_ + VAL_DIM_) {
        const int c3 = c0 - 2 * KEY_DIM_;
        col = ((c3 >> 8) * 768) + 256 + (c3 & 255);
        outp = vbuf + bs * VAL_DIM_ + c3;
    } else {
        const int zc = c0 - (2 * KEY_DIM_ + VAL_DIM_);
        const int hv = zc >> 7;
        col = (hv >> 1) * 768 + 512 + (hv & 1) * 128 + (zc & 127);
        outp = zbuf + bs * VAL_DIM_ + zc;
    }
    const bf16* xp = qkvz + bs * (int64_t)QKVZ_DIM_ + col;
    if (c0 >= 2 * KEY_DIM_ + VAL_DIM_) {
        *(uint4*)outp = *(const uint4*)xp;   // z passthrough
        return;
    }
    const uint4 zero4 = {0u, 0u, 0u, 0u};
    const uint4 x0 = *(const uint4*)xp;
    const uint4 x1 = (s >= 1) ? *(const uint4*)(xp - QKVZ_DIM_) : zero4;
    const uint4 x2 = (s >= 2) ? *(const uint4*)(xp - 2 * QKVZ_DIM_) : zero4;
    const uint4 x3 = (s >= 3) ? *(const uint4*)(xp - 3 * QKVZ_DIM_) : zero4;
    float y[8];
#pragma unroll
    for (int j = 0; j < 8; ++j) {
        const float4 wv = *(const float4*)(cw + (size_t)(c0 + j) * 4);
        float acc = wv.w * bf_lane(x0, j);
        acc = fmaf(wv.z, bf_lane(x1, j), acc);
        acc = fmaf(wv.y, bf_lane(x2, j), acc);
        acc = fmaf(wv.x, bf_lane(x3, j), acc);
        y[j] = silu_f(acc);
    }
    float sc = 1.f;
    if (c0 < 2 * KEY_DIM_) {   // q or k: l2norm across the 128-ch head row
        float ss = 0.f;
#pragma unroll
        for (int j = 0; j < 8; ++j) ss = fmaf(y[j], y[j], ss);
        ss = row16_sum(ss);    // 16 lanes x 8 ch = one head row
        sc = rsqrtf(ss + EPS_);
        if (c0 < KEY_DIM_) sc *= 0.08838834764831845f;  // DK^-0.5 for q
    }
    u16x8 o;
#pragma unroll
    for (int j = 0; j < 8; ++j) o[j] = f2bf(y[j] * sc);
    *(u16x8*)outp = o;
}

// ---------------------------------------------------------------------------
// Gate precompute from 4 K-split partials
// ---------------------------------------------------------------------------
__global__ __launch_bounds__(256) void gate_kernel(
    const float* __restrict__ ba_part, const float* __restrict__ A_log,
    const float* __restrict__ dt_bias, float* __restrict__ gbuf,
    float* __restrict__ betabuf) {
    const int idx = blockIdx.x * 256 + threadIdx.x;   // B*S*HV
    const int hv = idx & (HV_ - 1);
    const int bs = idx >> 5;
    const int hk = hv >> 1, j = hv & 1;
    const size_t SP = (size_t)B_ * S_ * 64;  // 262144
    const float* p = ba_part + (size_t)bs * 64 + hk * 4;
    const float bval = p[j] + p[SP + j] + p[2 * SP + j] + p[3 * SP + j];
    const float aval =
        p[2 + j] + p[SP + 2 + j] + p[2 * SP + 2 + j] + p[3 * SP + 2 + j];
    const float x = aval + dt_bias[hv];
    const float sp = (x > 20.f) ? x : log1pf(expf(x));
    gbuf[idx] = -expf(A_log[hv]) * sp;
    betabuf[idx] = 1.f / (1.f + expf(-bval));
}

// ---------------------------------------------------------------------------
// PASS 1 — R15 structure (register substitution + wave specialization).
// ---------------------------------------------------------------------------
__global__ __launch_bounds__(256) void p1_kernel(
    const bf16* __restrict__ qbf, const bf16* __restrict__ kbf,
    const bf16* __restrict__ vbuf, const float* __restrict__ gbuf,
    const float* __restrict__ betabuf, bf16* __restrict__ WkA,
    bf16* __restrict__ QgA, bf16* __restrict__ Kg2A, bf16* __restrict__ UA,
    bf16* __restrict__ LA, float* __restrict__ gcArr) {
    const int ch = blockIdx.x;          // bh*32 + c
    const int bh = ch >> 5, c = ch & 31;
    const int b = bh >> 5, hv = bh & 31;
    const int hk = hv >> 1;
    const int tid = threadIdx.x;
    const int w = tid >> 6, l = tid & 63;
    const int fl = l & 15, fk = (l >> 4) * 8;

    __shared__ float Gls[CL_];
    __shared__ float Bls[CL_];
    __shared__ float Egt[CL_];          // exp(G_t)
    __shared__ float Egc[CL_];          // exp(G63 - G_t)
    __shared__ float A_ls[CL_][CL_ + 1];
    __shared__ bf16 Tbf[CL_ * CL_];
    __shared__ bf16 Vt[128 * 72];
    __shared__ bf16 Kt[128 * 72];

    if (tid < 64) {
        float G = gbuf[((size_t)(b * S_ + c * 64 + tid)) * HV_ + hv];
        Bls[tid] = betabuf[((size_t)(b * S_ + c * 64 + tid)) * HV_ + hv];
#pragma unroll
        for (int d = 1; d < 64; d <<= 1) {
            const float n = __shfl_up(G, d, 64);
            if (tid >= d) G += n;
        }
        Gls[tid] = G;
        const float eg = expf(G);
        Egt[tid] = eg;
        Egc[tid] = expf(__shfl(G, 63, 64) - G);
        if (tid == 63) gcArr[ch] = eg;
    }
    __syncthreads();

    const bf16* kc = kbf + ((size_t)(b * S_ + c * 64)) * KEY_DIM_ + hk * DK_;
    const bf16* qc = qbf + ((size_t)(b * S_ + c * 64)) * KEY_DIM_ + hk * DK_;
    bf16* LC = LA + (size_t)ch * 4096;

    f32x4 accK[4], accQ[4];
#pragma unroll
    for (int n = 0; n < 4; ++n) {
        accK[n] = (f32x4){0.f, 0.f, 0.f, 0.f};
        accQ[n] = (f32x4){0.f, 0.f, 0.f, 0.f};
    }
#pragma unroll
    for (int kk = 0; kk < 4; ++kk) {
        const bf16x8 aK =
            *(const bf16x8*)(kc + (size_t)(w * 16 + fl) * KEY_DIM_ + fk + 32 * kk);
        const bf16x8 aQ =
            *(const bf16x8*)(qc + (size_t)(w * 16 + fl) * KEY_DIM_ + fk + 32 * kk);
#pragma unroll
        for (int n = 0; n < 4; ++n) {
            const bf16x8 bK = *(const bf16x8*)(kc + (size_t)(n * 16 + fl) * KEY_DIM_ +
                                               fk + 32 * kk);
            accK[n] = MFMA16(aK, bK, accK[n]);
            accQ[n] = MFMA16(aQ, bK, accQ[n]);
        }
    }
#pragma unroll
    for (int n = 0; n < 4; ++n)
#pragma unroll
        for (int r = 0; r < 4; ++r) {
            const int t = w * 16 + (l >> 4) * 4 + r;
            const int s = n * 16 + fl;
            const float eg = expf(Gls[t] - Gls[s]);
            A_ls[t][s] = (s < t) ? Bls[t] * eg * accK[n][r] : 0.f;
            const float lv = (s <= t) ? eg * accQ[n][r] : 0.f;
            LC[t * 64 + s] = f2bf(lv);
        }
    __syncthreads();

    bf16* QgC = QgA + (size_t)ch * 8192;
    bf16* KgC = Kg2A + (size_t)ch * 8192;

    if (w == 0) {
        float Tcol[64];
#pragma unroll
        for (int t = 0; t < 64; ++t) {
            float acc = (t == l) ? 1.f : 0.f;
#pragma unroll
            for (int s = 0; s < t; ++s)
                acc = fmaf(-A_ls[t][s], Tcol[s], acc);
            Tcol[t] = acc;
            Tbf[t * 64 + l] = f2bf(acc);
        }
    } else if (w == 1) {
        for (int i = l; i < 8192; i += 64) {
            const int d = i & 127, s = i >> 7;
            Vt[d * 72 + s] = f2bf(
                bf2f(vbuf[((size_t)(b * S_ + c * 64 + s)) * VAL_DIM_ + hv * DV_ + d]) *
                Bls[s]);
        }
    } else if (w == 2) {
        for (int i = l; i < 8192; i += 64) {
            const int d = i & 127, s = i >> 7;
            Kt[d * 72 + s] =
                f2bf(bf2f(kc[(size_t)s * KEY_DIM_ + d]) * Bls[s] * Egt[s]);
        }
    } else {
        for (int i = l; i < 8192; i += 64) {
            const int d = i & 127, t = i >> 7;
            QgC[t * 128 + d] = f2bf(bf2f(qc[(size_t)t * KEY_DIM_ + d]) * Egt[t]);
            KgC[d * 64 + t] = f2bf(bf2f(kc[(size_t)t * KEY_DIM_ + d]) * Egc[t]);
        }
    }
    __syncthreads();

    bf16* UC = UA + (size_t)ch * 8192;
    bf16* WkC = WkA + (size_t)ch * 8192;
    f32x4 accU[8], accW[8];
#pragma unroll
    for (int n = 0; n < 8; ++n) {
        accU[n] = (f32x4){0.f, 0.f, 0.f, 0.f};
        accW[n] = (f32x4){0.f, 0.f, 0.f, 0.f};
    }
#pragma unroll
    for (int kk = 0; kk < 2; ++kk) {
        const bf16x8 aT = *(const bf16x8*)(Tbf + (w * 16 + fl) * 64 + fk + 32 * kk);
#pragma unroll
        for (int n = 0; n < 8; ++n) {
            const bf16x8 bV = *(const bf16x8*)(Vt + (n * 16 + fl) * 72 + fk + 32 * kk);
            const bf16x8 bK2 = *(const bf16x8*)(Kt + (n * 16 + fl) * 72 + fk + 32 * kk);
            accU[n] = MFMA16(aT, bV, accU[n]);
            accW[n] = MFMA16(aT, bK2, accW[n]);
        }
    }
#pragma unroll
    for (int n = 0; n < 8; ++n)
#pragma unroll
        for (int r = 0; r < 4; ++r) {
            const int t = w * 16 + (l >> 4) * 4 + r;
            const int col = n * 16 + fl;
            UC[t * 128 + col] = f2bf(accU[n][r]);
            WkC[t * 128 + col] = f2bf(accW[n][r]);
        }
}

// ---------------------------------------------------------------------------
// PASS 2 — unchanged from R12.
// ---------------------------------------------------------------------------
__global__ __launch_bounds__(256) void p2_kernel(
    const bf16* __restrict__ WkA, const bf16* __restrict__ QgA,
    const bf16* __restrict__ Kg2A, const bf16* __restrict__ UA,
    const bf16* __restrict__ LA, const float* __restrict__ gcArr,
    bf16* __restrict__ core) {
    const int xcd = blockIdx.x & 7;
    const int rr = blockIdx.x >> 3;       // 0..31
    const int bh = xcd * 8 + (rr & 7);    // 0..63
    const int dvb = rr >> 3;              // 0..3
    const int b = bh >> 5, hv = bh & 31;
    const int tid = threadIdx.x;
    const int w = tid >> 6, l = tid & 63;
    const int fl = l & 15, fk = (l >> 4) * 8;

    __shared__ bf16 Sbf[32 * 136];
    __shared__ bf16 Dbf[32 * 72];

    for (int i = tid; i < 32 * 136; i += 256) Sbf[i] = 0;
    f32x4 accS[2][2];
#pragma unroll
    for (int m = 0; m < 2; ++m)
#pragma unroll
        for (int n = 0; n < 2; ++n) accS[m][n] = (f32x4){0.f, 0.f, 0.f, 0.f};
    __syncthreads();

    for (int c = 0; c < NCHUNK_; ++c) {
        const size_t ch = (size_t)bh * 32 + c;
        const bf16* WkC = WkA + ch * 8192;
        const bf16* QgC = QgA + ch * 8192;
        const bf16* KgC = Kg2A + ch * 8192;
        const bf16* UC = UA + ch * 8192;
        const bf16* LC = LA + ch * 4096;

        f32x4 accD[2], accO[2];
#pragma unroll
        for (int n = 0; n < 2; ++n) {
            accD[n] = (f32x4){0.f, 0.f, 0.f, 0.f};
            accO[n] = (f32x4){0.f, 0.f, 0.f, 0.f};
        }
#pragma unroll
        for (int kk = 0; kk < 4; ++kk) {
            const bf16x8 bS0 = *(const bf16x8*)(Sbf + (0 * 16 + fl) * 136 + fk + 32 * kk);
            const bf16x8 bS1 = *(const bf16x8*)(Sbf + (1 * 16 + fl) * 136 + fk + 32 * kk);
            const bf16x8 aW = *(const bf16x8*)(WkC + (w * 16 + fl) * 128 + fk + 32 * kk);
            const bf16x8 aQ = *(const bf16x8*)(QgC + (w * 16 + fl) * 128 + fk + 32 * kk);
            accD[0] = MFMA16(aW, bS0, accD[0]);
            accD[1] = MFMA16(aW, bS1, accD[1]);
            accO[0] = MFMA16(aQ, bS0, accO[0]);
            accO[1] = MFMA16(aQ, bS1, accO[1]);
        }
#pragma unroll
        for (int n = 0; n < 2; ++n)
#pragma unroll
            for (int r = 0; r < 4; ++r) {
                const int t = w * 16 + (l >> 4) * 4 + r;
                const int dvl = n * 16 + fl;
                const float u = bf2f(UC[t * 128 + dvb * 32 + dvl]);
                Dbf[dvl * 72 + t] = f2bf(u - accD[n][r]);
            }
        __syncthreads();

#pragma unroll
        for (int kk = 0; kk < 2; ++kk) {
            const bf16x8 bD0 = *(const bf16x8*)(Dbf + (0 * 16 + fl) * 72 + fk + 32 * kk);
            const bf16x8 bD1 = *(const bf16x8*)(Dbf + (1 * 16 + fl) * 72 + fk + 32 * kk);
            const bf16x8 aL = *(const bf16x8*)(LC + (w * 16 + fl) * 64 + fk + 32 * kk);
            accO[0] = MFMA16(aL, bD0, accO[0]);
            accO[1] = MFMA16(aL, bD1, accO[1]);
        }
#pragma unroll
        for (int n = 0; n < 2; ++n)
#pragma unroll
            for (int r = 0; r < 4; ++r) {
                const int t = w * 16 + (l >> 4) * 4 + r;
                const int col = hv * 128 + dvb * 32 + n * 16 + fl;
                core[((size_t)(b * S_ + c * 64 + t)) * VAL_DIM_ + col] =
                    f2bf(accO[n][r]);
            }

        const float gc = gcArr[ch];
#pragma unroll
        for (int m = 0; m < 2; ++m)
#pragma unroll
            for (int n = 0; n < 2; ++n)
#pragma unroll
                for (int r = 0; r < 4; ++r) accS[m][n][r] *= gc;
#pragma unroll
        for (int kk = 0; kk < 2; ++kk) {
            const bf16x8 bD0 = *(const bf16x8*)(Dbf + (0 * 16 + fl) * 72 + fk + 32 * kk);
            const bf16x8 bD1 = *(const bf16x8*)(Dbf + (1 * 16 + fl) * 72 + fk + 32 * kk);
#pragma unroll
            for (int m = 0; m < 2; ++m) {
                const bf16x8 aK =
                    *(const bf16x8*)(KgC + ((2 * w + m) * 16 + fl) * 64 + fk + 32 * kk);
                accS[m][0] = MFMA16(aK, bD0, accS[m][0]);
                accS[m][1] = MFMA16(aK, bD1, accS[m][1]);
            }
        }
        __syncthreads();
#pragma unroll
        for (int m = 0; m < 2; ++m)
#pragma unroll
            for (int n = 0; n < 2; ++n)
#pragma unroll
                for (int r = 0; r < 4; ++r) {
                    const int dk = (2 * w + m) * 16 + (l >> 4) * 4 + r;
                    const int dvl = n * 16 + fl;
                    Sbf[dvl * 136 + dk] = f2bf(accS[m][n][r]);
                }
        __syncthreads();
    }
}

// ---------------------------------------------------------------------------
// Gated RMSNorm in-place on bf16 core; z from zbuf (contiguous).
// ---------------------------------------------------------------------------
__global__ __launch_bounds__(256) void rmsnorm_gate_kernel(
    bf16* __restrict__ core, const bf16* __restrict__ zbuf,
    const float* __restrict__ nw) {
    const int wid = (blockIdx.x * 256 + threadIdx.x) >> 6;
    const int lane = threadIdx.x & 63;
    const int hv = wid & (HV_ - 1);
    const int64_t bs = wid >> 5;
    bf16* x = core + (size_t)bs * VAL_DIM_ + hv * DV_;
    const float x0 = bf2f(x[lane]);
    const float x1 = bf2f(x[lane + 64]);
    float ss = fmaf(x0, x0, x1 * x1);
#pragma unroll
    for (int m = 1; m < 64; m <<= 1) ss += __shfl_xor(ss, m);
    const float inv = rsqrtf(ss * (1.f / 128.f) + EPS_);
    const bf16* z = zbuf + (size_t)bs * VAL_DIM_ + hv * DV_;
    x[lane] = f2bf(x0 * inv * nw[lane] * silu_f(bf2f(z[lane])));
    x[lane + 64] =
        f2bf(x1 * inv * nw[lane + 64] * silu_f(bf2f(z[lane + 64])));
}

// ---------------------------------------------------------------------------
extern "C" void kernel_launch(void* const* d_in, const int* in_sizes, int n_in,
                              void* d_out, int out_size, void* d_ws,
                              size_t ws_size, hipStream_t stream) {
    const float* hidden  = (const float*)d_in[0];
    const float* W_qkvz  = (const float*)d_in[1];
    const float* W_ba    = (const float*)d_in[2];
    const float* conv_w  = (const float*)d_in[3];
    const float* dt_bias = (const float*)d_in[4];
    const float* A_log   = (const float*)d_in[5];
    const float* norm_w  = (const float*)d_in[6];
    const float* W_out   = (const float*)d_in[7];
    float* out = (float*)d_out;

    // ---- workspace (~324 MB <= proven 337.5) ----
    bf16* R = (bf16*)d_ws;
    bf16* hidden_bf = R;                         //  8,388,608 e
    bf16* Wq_bf = R + (size_t)8388608;           // 25,165,824 e
    bf16* qkvz  = R + (size_t)33554432;          // 50,331,648 e
    // P1 aliases (valid once conv has consumed qkvz):
    bf16* WkA  = R;                              // 16,777,216 e
    bf16* QgA  = R + (size_t)16777216;           // 16,777,216 e
    bf16* Kg2A = R + (size_t)33554432;           // 16,777,216 e
    bf16* UA   = R + (size_t)50331648;           // 16,777,216 e
    bf16* LA   = R + (size_t)67108864;           //  8,388,608 e
    // non-aliased:
    bf16* Wo_bf = R + (size_t)83886080;          //  8,388,608 e
    bf16* qbf   = Wo_bf + (size_t)8388608;       //  8,388,608 e
    bf16* kbf   = qbf + (size_t)8388608;         //  8,388,608 e
    bf16* vbuf  = kbf + (size_t)8388608;         // 16,777,216 e
    bf16* zbuf  = vbuf + (size_t)16777216;       // 16,777,216 e
    bf16* core  = zbuf + (size_t)16777216;       // 16,777,216 e
    float* ba_part = (float*)(core + (size_t)16777216);  // 1,048,576 f
    float* gbuf    = ba_part + 1048576;                  //   131,072 f
    float* betabuf = gbuf + 131072;                      //   131,072 f
    float* gcArr   = betabuf + 131072;                   //     2,048 f

    const int MBS = B_ * S_;  // 4096

    // 0. fp32 -> bf16 operand conversion (one fused launch)
    f2bf3_kernel<<<40960, 256, 0, stream>>>(hidden, W_qkvz, W_out, hidden_bf,
                                            Wq_bf, Wo_bf);

    // 1. qkvz = hidden @ W_qkvz^T (256x256 tiles — best measured: 189us)
    gemm256_nt<256, 256, 1><<<dim3(QKVZ_DIM_ / 256, MBS / 256), 512, 0,
                              stream>>>(hidden_bf, Wq_bf, (void*)qkvz, MBS,
                                        QKVZ_DIM_, HID_);
    // 2. ba = hidden @ W_ba^T (fp32, K-split x4)
    gemm_ba_ksplit<<<dim3(4, 64), 256, 0, stream>>>(hidden, W_ba, ba_part);
    // 3. gates
    gate_kernel<<<(MBS * HV_) / 256, 256, 0, stream>>>(ba_part, A_log, dt_bias,
                                                       gbuf, betabuf);
    // 4. conv + silu + fused q/k l2norm + z copy
    conv_silu_kernel<<<(int)(((int64_t)MBS * 1536) / 256), 256, 0, stream>>>(
        qkvz, conv_w, qbf, kbf, vbuf, zbuf);
    // 5. chunked delta rule
    p1_kernel<<<2048, 256, 0, stream>>>(qbf, kbf, vbuf, gbuf, betabuf, WkA,
                                        QgA, Kg2A, UA, LA, gcArr);
    p2_kernel<<<256, 256, 0, stream>>>(WkA, QgA, Kg2A, UA, LA, gcArr, core);
    // 6. gated rmsnorm
    rmsnorm_gate_kernel<<<(MBS * HV_ * 64) / 256, 256, 0, stream>>>(core, zbuf,
                                                                    norm_w);
    // 7. out = core @ W_out^T (128x128 tiles, 512 WGs, fp32 out)
    gemm256_nt<128, 128, 0><<<dim3(HID_ / 128, MBS / 128), 512, 0, stream>>>(
        core, Wo_bf, (void*)out, MBS, HID_, VAL_DIM_);
}